// Round 7
// baseline (214.665 us; speedup 1.0000x reference)
//
#include <hip/hip_runtime.h>
#include <hip/hip_bf16.h>
#include <stdint.h>

typedef float  f32x4  __attribute__((ext_vector_type(4)));
typedef float  f32x16 __attribute__((ext_vector_type(16)));
typedef short  s16x8  __attribute__((ext_vector_type(8)));

#define GLOAD_LDS16(g, l)                                                          \
  __builtin_amdgcn_global_load_lds(                                               \
      (const __attribute__((address_space(1))) unsigned int*)(g),                 \
      (__attribute__((address_space(3))) unsigned int*)(l), 16, 0, 0)

#define WAITVM_(N) asm volatile("s_waitcnt vmcnt(" #N ")" ::: "memory")
#define WAITVM(N) WAITVM_(N)
#define WAITLGKM0 asm volatile("s_waitcnt lgkmcnt(0)" ::: "memory")

static __device__ __forceinline__ unsigned short f2bf(float f) {
  union { __hip_bfloat16 b; unsigned short s; } cv;
  cv.b = __float2bfloat16(f);          // RNE; compiler pairs into v_cvt_pk_bf16_f32
  return cv.s;
}

static __device__ __forceinline__ int swz_e(int r) { return ((r & 3) ^ ((r >> 2) & 1)); }
static __device__ __forceinline__ int swz_byte(int r, int c) {
  return r * 64 + (((c ^ swz_e(r)) & 3) << 4);
}

// ---------------- pre-pass: Wt[k-1][col][d] = bf16(W[k][d][col]), k = 1..8 ----------------
__global__ __launch_bounds__(256) void transpose_w(const float* __restrict__ w,
                                                   short* __restrict__ wt) {
  __shared__ unsigned int lds[64 * 33];
  const int t = threadIdx.x;
  const int bid = blockIdx.x;
  const int kb = bid >> 8;            // 0..7  (k = kb+1)
  const int db = (bid >> 4) & 15;
  const int cb = bid & 15;
  const int d0 = db * 64, c0 = cb * 64;
  const float* src = w + (size_t)(kb + 1) * 1048576 + (size_t)d0 * 1024 + c0;
  #pragma unroll
  for (int p = 0; p < 4; ++p) {
    int dl = p * 16 + (t >> 4);
    int c4 = (t & 15) * 4;
    f32x4 f = *(const f32x4*)(src + (size_t)dl * 1024 + c4);
    unsigned lo = (unsigned)f2bf(f.x) | ((unsigned)f2bf(f.y) << 16);
    unsigned hi = (unsigned)f2bf(f.z) | ((unsigned)f2bf(f.w) << 16);
    lds[dl * 33 + (t & 15) * 2]     = lo;
    lds[dl * 33 + (t & 15) * 2 + 1] = hi;
  }
  __syncthreads();
  const int col = t >> 2;   // 0..63
  const int dc  = t & 3;    // 16-d chunk
  union { unsigned short u[8]; s16x8 v; } o0, o1;
  #pragma unroll
  for (int j = 0; j < 16; ++j) {
    int dl = dc * 16 + j;
    unsigned word = lds[dl * 33 + (col >> 1)];
    unsigned short e = (col & 1) ? (unsigned short)(word >> 16) : (unsigned short)(word & 0xffffu);
    if (j < 8) o0.u[j] = e; else o1.u[j - 8] = e;
  }
  short* dst = wt + ((size_t)(kb * 1024 + c0 + col) * 1024 + d0 + dc * 16);
  *(s16x8*)dst       = o0.v;
  *(s16x8*)(dst + 8) = o1.v;
}

// ---------------- bias[c] = sum_d W[0][d][c] ----------------
__global__ __launch_bounds__(256) void bias_k(const float* __restrict__ w,
                                              float* __restrict__ b) {
  __shared__ float red[256];
  const int t = threadIdx.x;
  const int col = blockIdx.x * 64 + (t & 63);
  const int seg = t >> 6;
  float s = 0.f;
  const float* p = w + (size_t)(seg * 256) * 1024 + col;
  for (int d = 0; d < 256; ++d) s += p[(size_t)d * 1024];
  red[t] = s;
  __syncthreads();
  if (t < 64) b[col] = red[t] + red[t + 64] + red[t + 128] + red[t + 192];
}

// ---------------- out init: out[r][c] = bias[c] (or 0) ----------------
__global__ __launch_bounds__(256) void init_out(const float* __restrict__ bias,
                                                float* __restrict__ out, int has_bias) {
  const size_t i = (size_t)blockIdx.x * 256 + threadIdx.x;
  const int c = (int)((i * 4) & 1023);
  f32x4 v = has_bias ? *(const f32x4*)(bias + c) : (f32x4){0.f, 0.f, 0.f, 0.f};
  *(f32x4*)(out + i * 4) = v;
}

// ---------------- fused Chebyshev GEMM ----------------
// R6 skeleton (counted vmcnt(4), 3-buf B DMA, XCD-pinned (nb,kb), dbuf A, x-prefetch).
// Round-7 deltas: (1) mfma_f32_32x32x16_bf16 (16 MFMA/step instead of 32;
// matrix-pipe 160->128 cyc/step, -16 issue slots); (2) s_setprio removed (m190:
// null-to-negative on lockstep GEMM).
template <bool USE_WS>
__global__ __launch_bounds__(256, 2) void cheb_gemm(
    const float* __restrict__ x, const float* __restrict__ w,
    const short* __restrict__ wt, float* __restrict__ out) {
  __shared__ short Asm[2][4096];   // 2 x 8KB  [128 rows][32 dims] swizzled
  __shared__ short Bsm[3][8192];   // 3 x 16KB [256 cols][32 dims] swizzled

  const int tid = threadIdx.x, lane = tid & 63, wid = tid >> 6;
  const int bid = blockIdx.x;
  const int xcd = bid & 7;
  const int mb  = bid >> 3;            // 0..63
  const int nb  = xcd >> 1, kb = xcd & 1;
  const int rowbase = mb * 128, colbase = nb * 256;
  const int kbase = kb * 512;
  const int wr = wid >> 1, wc = wid & 1;

  // A generation: thread owns row (tid&127), dims h*16 .. +16 of each strip
  const int arow = tid & 127, h = tid >> 7;
  const int aw0 = swz_byte(arow, 2 * h), aw1 = swz_byte(arow, 2 * h + 1);
  const float* xrow = x + (size_t)(rowbase + arow) * 1024 + kbase + h * 16;

  float p1[16], p2[16];
  unsigned x2h[8];     // 2x packed f16x2 (numerics validated rounds 3-6)
  f32x4 xq[4];         // x for the NEXT strip (prefetched 5+ steps early)

  if constexpr (USE_WS) {
    // ---- 32x32x16 fragment geometry ----
    const int la32 = lane & 31, hi = lane >> 5;
    const int e32  = (la32 & 3) ^ ((la32 >> 2) & 1);
    // frag byte offsets within a tile buffer (rows/cols stride 64B, XOR swizzle)
    int aoff[2][2], boff[4][2];
    #pragma unroll
    for (int m = 0; m < 2; ++m)
      #pragma unroll
      for (int sub = 0; sub < 2; ++sub)
        aoff[m][sub] = (wr * 64 + m * 32 + la32) * 64 + (((sub * 2 + hi) ^ e32) << 4);
    #pragma unroll
    for (int n = 0; n < 4; ++n)
      #pragma unroll
      for (int sub = 0; sub < 2; ++sub)
        boff[n][sub] = (wc * 128 + n * 32 + la32) * 64 + (((sub * 2 + hi) ^ e32) << 4);

    f32x16 acc[2][4];
    #pragma unroll
    for (int m = 0; m < 2; ++m)
      #pragma unroll
      for (int n = 0; n < 4; ++n)
        #pragma unroll
        for (int i = 0; i < 16; ++i) acc[m][n][i] = 0.f;

    // per-lane pre-swizzled gload source; tile j-offset = j*16384 shorts
    const int bcol0  = wid * 64 + (lane >> 2);
    const int goff   = ((lane & 3) ^ swz_e(lane >> 2)) * 8;
    const short* gptr = wt + (size_t)(colbase + bcol0) * 1024 + kbase + goff; // tile 0

#define ISSUE_AT(PTR, WOFF)                                                        \
    { _Pragma("unroll")                                                            \
      for (int j_ = 0; j_ < 4; ++j_)                                               \
        GLOAD_LDS16((PTR) + j_ * 16384,                                            \
                    (char*)&Bsm[0][0] + (WOFF) + (wid * 4 + j_) * 1024); }

    // ---- prologue ----
    #pragma unroll
    for (int q = 0; q < 4; ++q) xq[q] = *(const f32x4*)(xrow + q * 4);  // strip 0
    ISSUE_AT(gptr, 0);          gptr += 1048576;   // tile 0 -> buf 0
    ISSUE_AT(gptr, 16384);      gptr += 1048576;   // tile 1 -> buf 1 ; gptr at tile 2
    // GEN(0): T_1 = x (consumes xq strip 0) -> Asm[0]
    {
      union { unsigned short u[8]; s16x8 v; } o0, o1;
      #pragma unroll
      for (int i = 0; i < 16; ++i) { p1[i] = xq[i >> 2][i & 3]; p2[i] = 1.f; }
      #pragma unroll
      for (int i = 0; i < 8; ++i) {
        union { unsigned u; _Float16 f[2]; } t2;
        t2.f[0] = (_Float16)(p1[2 * i] + p1[2 * i]);
        t2.f[1] = (_Float16)(p1[2 * i + 1] + p1[2 * i + 1]);
        x2h[i] = t2.u;
        o0.u[i] = f2bf(p1[i]); o1.u[i] = f2bf(p1[i + 8]);
      }
      *(s16x8*)((char*)&Asm[0][0] + aw0) = o0.v;
      *(s16x8*)((char*)&Asm[0][0] + aw1) = o1.v;
    }
    WAITLGKM0;
    WAITVM(4);                       // tile 0 landed (tile 1 still in flight)
    __builtin_amdgcn_sched_barrier(0);
    __builtin_amdgcn_s_barrier();
    __builtin_amdgcn_sched_barrier(0);

    int wroff = 32768;               // LDS byte offset of buf for tile t+2
    int rdoff = 0;                   // buf for tile t
    int ard   = 0;                   // Asm byte offset for step t

    #pragma unroll 1
    for (int t = 0; t < 128; ++t) {
      // x prefetch for strip (t>>3)+1, 5 steps before its r==0 consumption
      if ((t & 7) == 2 && t < 120) {
        const float* xs = xrow + ((t >> 3) + 1) * 32;
        #pragma unroll
        for (int q = 0; q < 4; ++q) xq[q] = *(const f32x4*)(xs + q * 4);
      }
      // B prefetch, depth 2 (tile t+2)
      if (t + 2 < 128) {
        ISSUE_AT(gptr, wroff);
        gptr += ((t & 7) == 5) ? (32 - 7 * 1048576) : 1048576;
        wroff = (wroff == 32768) ? 0 : wroff + 16384;
      }
      // A for step t+1 -> Asm[(t+1)&1]
      if (t + 1 < 128) {
        const int rn = (t + 1) & 7;
        union { unsigned short u[8]; s16x8 v; } o0, o1;
        if (rn == 0) {
          #pragma unroll
          for (int i = 0; i < 16; ++i) { p1[i] = xq[i >> 2][i & 3]; p2[i] = 1.f; }
          #pragma unroll
          for (int i = 0; i < 8; ++i) {
            union { unsigned u; _Float16 f[2]; } t2;
            t2.f[0] = (_Float16)(p1[2 * i] + p1[2 * i]);
            t2.f[1] = (_Float16)(p1[2 * i + 1] + p1[2 * i + 1]);
            x2h[i] = t2.u;
            o0.u[i] = f2bf(p1[i]); o1.u[i] = f2bf(p1[i + 8]);
          }
        } else {
          #pragma unroll
          for (int i = 0; i < 16; ++i) {
            union { unsigned u; _Float16 f[2]; } t2; t2.u = x2h[i >> 1];
            float cur = fmaf((float)t2.f[i & 1], p1[i], -p2[i]);
            p2[i] = p1[i]; p1[i] = cur;
            unsigned short e = f2bf(cur);
            if (i < 8) o0.u[i] = e; else o1.u[i - 8] = e;
          }
        }
        *(s16x8*)((char*)&Asm[0][0] + (ard ^ 8192) + aw0) = o0.v;
        *(s16x8*)((char*)&Asm[0][0] + (ard ^ 8192) + aw1) = o1.v;
      }
      // MFMA on (Asm[t&1], Bsm[t%3]) : 16 x mfma_f32_32x32x16_bf16
      s16x8 af[2][2];
      #pragma unroll
      for (int m = 0; m < 2; ++m)
        #pragma unroll
        for (int sub = 0; sub < 2; ++sub)
          af[m][sub] = *(const s16x8*)((char*)&Asm[0][0] + ard + aoff[m][sub]);
      #pragma unroll
      for (int sub = 0; sub < 2; ++sub) {
        #pragma unroll
        for (int n = 0; n < 4; ++n) {
          s16x8 bfr = *(const s16x8*)((char*)&Bsm[0][0] + rdoff + boff[n][sub]);
          #pragma unroll
          for (int m = 0; m < 2; ++m)
            acc[m][n] = __builtin_amdgcn_mfma_f32_32x32x16_bf16(af[m][sub], bfr, acc[m][n], 0, 0, 0);
        }
      }
      // end-of-step: A writes visible; tile t+1 landed; NO full drain
      WAITLGKM0;
      if (t < 126) { WAITVM(4); } else { WAITVM(0); }
      __builtin_amdgcn_sched_barrier(0);
      __builtin_amdgcn_s_barrier();
      __builtin_amdgcn_sched_barrier(0);
      rdoff = (rdoff == 32768) ? 0 : rdoff + 16384;
      ard ^= 8192;
    }
#undef ISSUE_AT

    // epilogue: out += acc (split-K partial), hardware f32 atomics
    // 32x32 C-layout (m74/m101): col = lane&31, row = (reg&3) + 8*(reg>>2) + 4*(lane>>5)
    #pragma unroll
    for (int m = 0; m < 2; ++m) {
      #pragma unroll
      for (int n = 0; n < 4; ++n) {
        const int c = colbase + wc * 128 + n * 32 + la32;
        #pragma unroll
        for (int g = 0; g < 4; ++g) {
          const int r0 = rowbase + wr * 64 + m * 32 + g * 8 + hi * 4;
          #pragma unroll
          for (int j = 0; j < 4; ++j)
            unsafeAtomicAdd(&out[(size_t)(r0 + j) * 1024 + c], acc[m][n][g * 4 + j]);
        }
      }
    }
  } else {
    // fallback (no workspace): single-buffer, f32->bf16 staging, k=0..8, 16x16 MFMA
    const int la = lane & 15, lg = lane >> 4;
    const int e_la = (la & 3) ^ ((la >> 2) & 1);
    const int abase = (wr * 64 + la) * 64 + ((lg ^ e_la) << 4);
    const int bbase = (wc * 128 + la) * 64 + ((lg ^ e_la) << 4);
    f32x4 acc[4][8];
    #pragma unroll
    for (int m = 0; m < 4; ++m)
      #pragma unroll
      for (int n = 0; n < 8; ++n) acc[m][n] = (f32x4){0.f, 0.f, 0.f, 0.f};

    #pragma unroll 1
    for (int s = 0; s < 144; ++s) {
      const int r = s % 9, st = s / 9;
      const int d0 = kbase + st * 32;
      __syncthreads();
      { const int dd = tid & 31, cg = tid >> 5;
        const float* ws_ = w + (size_t)r * 1048576 + (size_t)(d0 + dd) * 1024 + colbase + cg * 4;
        #pragma unroll
        for (int p_ = 0; p_ < 8; ++p_) {
          f32x4 f_ = *(const f32x4*)(ws_ + p_ * 32);
          #pragma unroll
          for (int jj = 0; jj < 4; ++jj) {
            int col = cg * 4 + p_ * 32 + jj;
            int byt = col * 64 + ((dd & 7) << 1) + ((((dd >> 3) ^ swz_e(col)) & 3) << 4);
            *(unsigned short*)((char*)&Bsm[0][0] + byt) = f2bf(f_[jj]);
          } } }
      union { unsigned short u[8]; s16x8 v; } o0, o1;
      if (r == 0) {
        #pragma unroll
        for (int q = 0; q < 4; ++q) xq[q] = *(const f32x4*)(xrow + st * 32 + q * 4);
        #pragma unroll
        for (int i = 0; i < 16; ++i) { p1[i] = xq[i >> 2][i & 3]; p2[i] = 1.f; }
        #pragma unroll
        for (int i = 0; i < 8; ++i) {
          union { unsigned u; _Float16 f[2]; } t2;
          t2.f[0] = (_Float16)(p1[2 * i] + p1[2 * i]);
          t2.f[1] = (_Float16)(p1[2 * i + 1] + p1[2 * i + 1]);
          x2h[i] = t2.u;
          o0.u[i] = 0x3f80; o1.u[i] = 0x3f80;   // T_0 = 1
        }
      } else if (r == 1) {
        #pragma unroll
        for (int i = 0; i < 8; ++i) { o0.u[i] = f2bf(p1[i]); o1.u[i] = f2bf(p1[i + 8]); }
      } else {
        #pragma unroll
        for (int i = 0; i < 16; ++i) {
          union { unsigned u; _Float16 f[2]; } t2; t2.u = x2h[i >> 1];
          float cur = fmaf((float)t2.f[i & 1], p1[i], -p2[i]);
          p2[i] = p1[i]; p1[i] = cur;
          if (i < 8) o0.u[i] = f2bf(cur); else o1.u[i - 8] = f2bf(cur);
        }
      }
      *(s16x8*)((char*)&Asm[0][0] + aw0) = o0.v;
      *(s16x8*)((char*)&Asm[0][0] + aw1) = o1.v;
      __syncthreads();
      s16x8 af[4];
      #pragma unroll
      for (int m = 0; m < 4; ++m)
        af[m] = *(const s16x8*)((char*)&Asm[0][0] + abase + m * 1024);
      #pragma unroll
      for (int n = 0; n < 8; ++n) {
        s16x8 bfr = *(const s16x8*)((char*)&Bsm[0][0] + bbase + n * 1024);
        #pragma unroll
        for (int m = 0; m < 4; ++m)
          acc[m][n] = __builtin_amdgcn_mfma_f32_16x16x32_bf16(af[m], bfr, acc[m][n], 0, 0, 0);
      }
    }

    #pragma unroll
    for (int m = 0; m < 4; ++m) {
      const int r0 = rowbase + wr * 64 + m * 16 + lg * 4;
      #pragma unroll
      for (int n = 0; n < 8; ++n) {
        const int c = colbase + wc * 128 + n * 16 + la;
        #pragma unroll
        for (int j = 0; j < 4; ++j)
          unsafeAtomicAdd(&out[(size_t)(r0 + j) * 1024 + c], acc[m][n][j]);
      }
    }
  }
}

extern "C" void kernel_launch(void* const* d_in, const int* in_sizes, int n_in,
                              void* d_out, int out_size, void* d_ws, size_t ws_size,
                              hipStream_t stream) {
  const float* x = (const float*)d_in[0];
  const float* w = (const float*)d_in[1];
  float* out = (float*)d_out;

  const size_t WT_BYTES = (size_t)8 * 1024 * 1024 * 2;   // 16 MiB
  const bool use_ws = ws_size >= WT_BYTES + 4096;

  if (use_ws) {
    short* wt   = (short*)d_ws;
    float* bias = (float*)((char*)d_ws + WT_BYTES);
    transpose_w<<<2048, 256, 0, stream>>>(w, wt);
    bias_k<<<16, 256, 0, stream>>>(w, bias);
    init_out<<<8192, 256, 0, stream>>>(bias, out, 1);
    cheb_gemm<true><<<512, 256, 0, stream>>>(x, w, wt, out);
  } else {
    init_out<<<8192, 256, 0, stream>>>(nullptr, out, 0);
    cheb_gemm<false><<<512, 256, 0, stream>>>(x, w, nullptr, out);
  }
}